// Round 12
// baseline (585.444 us; speedup 1.0000x reference)
//
#include <hip/hip_runtime.h>
#include <math.h>

// Shapes (fixed)
#define BB 2
#define HH 16
#define SS 2048
#define DD 1024
#define DK 64
#define BHS (BB*HH*SS)          // 65536
#define QSCALE 0.04508422f      // log2(e)/sqrt(1024): folded into q so softmax uses exp2

typedef short  bf16x8  __attribute__((ext_vector_type(8)));
typedef float  floatx4 __attribute__((ext_vector_type(4)));
typedef unsigned short u16;

#define MFMA(a,b,c) __builtin_amdgcn_mfma_f32_16x16x32_bf16((a),(b),(c),0,0,0)

// hardware packed conversion: dst.lo = bf16(lo), dst.hi = bf16(hi), RNE
__device__ __forceinline__ unsigned cvt_pk_bf16(float lo, float hi) {
    unsigned r;
    asm("v_cvt_pk_bf16_f32 %0, %1, %2" : "=v"(r) : "v"(lo), "v"(hi));
    return r;
}
__device__ __forceinline__ bf16x8 ldfrag(const u16* p) {
    union { uint4 u; bf16x8 b; } c;
    c.u = *(const uint4*)p;
    return c.b;
}
__device__ __forceinline__ void stbf4(u16* p, float4 t) {  // 4xf32 -> 4xbf16, 8B store
    union { unsigned u[2]; uint2 v; } c;
    c.u[0] = cvt_pk_bf16(t.x, t.y);
    c.u[1] = cvt_pk_bf16(t.z, t.w);
    *(uint2*)p = c.v;
}
// 4 f32 -> bf16 at p[0], p[16], p[32], p[48]  (C-fragment col stride 16)
__device__ __forceinline__ void st4s(u16* p, float a, float b, float c, float d) {
    unsigned x = cvt_pk_bf16(a, b), y = cvt_pk_bf16(c, d);
    p[0]  = (u16)x; p[16] = (u16)(x >> 16);
    p[32] = (u16)y; p[48] = (u16)(y >> 16);
}
// 2 f32 -> bf16 at p[0], p[16]
__device__ __forceinline__ void st2s(u16* p, float a, float b) {
    unsigned x = cvt_pk_bf16(a, b);
    p[0]  = (u16)x; p[16] = (u16)(x >> 16);
}

// ---------------------------------------------------------------------------
// Kernel 0: one-shot weight conversion fp32->bf16 (frozen).
// ---------------------------------------------------------------------------
#define WQKV_CHUNKS (192*1024/4)     // 49152 float4 chunks
#define WO_CHUNKS   (1024*1024/4)    // 262144
__global__ __launch_bounds__(256) void convert_w(
    const float* __restrict__ wq, const float* __restrict__ wk,
    const float* __restrict__ wv, const float* __restrict__ wo,
    u16* __restrict__ wqkv, u16* __restrict__ wo_bf)
{
    int i = blockIdx.x * 256 + threadIdx.x;
    if (i < WQKV_CHUNKS) {
        int r = i >> 8;            // row 0..191 (256 float4 per row)
        int c = i & 255;
        const float* src = (r < 64) ? wq : ((r < 128) ? wk : wv);
        float4 t = *(const float4*)(src + (size_t)(r & 63) * DD + c * 4);
        stbf4(wqkv + (size_t)r * DD + c * 4, t);
    } else if (i < WQKV_CHUNKS + WO_CHUNKS) {
        int j = i - WQKV_CHUNKS;
        float4 t = *(const float4*)(wo + (size_t)j * 4);
        stbf4(wo_bf + (size_t)j * 4, t);
    }
}

// ---------------------------------------------------------------------------
// Kernel 1: QKV projection v6 = v5 minus the W LDS staging.
// W (384 KB bf16, shared by all 1024 blocks) is L2-resident: read B-fragments
// DIRECTLY from global, exactly the addresses the LDS copy held. Removes
// 24 of 32 barriers + all W ds-traffic; LDS drops to Xq only (33.8 KB)
// -> 4 blocks/CU (was 2), doubling staging overlap. X 1KB-burst staging
// (R9's verified win) and epilogue unchanged; Vbuf overlays Xq behind an
// explicit barrier.
// ---------------------------------------------------------------------------
__global__ __launch_bounds__(512) void qkv_proj(
    const float* __restrict__ x, const u16* __restrict__ wqkv,
    u16* __restrict__ q, u16* __restrict__ k, u16* __restrict__ vT)
{
    __shared__ __align__(16) u16 Xq[64][264];   // 33.8 KB quarter-K X panel
    const int tid  = threadIdx.x;
    const int w    = tid >> 6;
    const int lane = tid & 63;
    const int quad = lane >> 4;
    const int l16  = lane & 15;
    const int rt   = w & 3;
    const int g    = w >> 2;
    const int rowbase = blockIdx.x * 64;

    floatx4 acc[6];
#pragma unroll
    for (int j = 0; j < 6; ++j) acc[j] = (floatx4){0.f,0.f,0.f,0.f};

    for (int qd = 0; qd < 4; ++qd) {
        if (qd) __syncthreads();   // all waves done reading Xq(qd-1)
        // stage X quarter: 64 rows x 256 cols fp32 -> bf16 (1 KB row-runs)
#pragma unroll
        for (int it = 0; it < 8; ++it) {
            int li = tid + it * 512;
            int r  = li >> 6, c4 = li & 63;
            float4 t = *(const float4*)(x + (size_t)(rowbase + r) * DD
                                          + qd * 256 + c4 * 4);
            stbf4(&Xq[r][c4 * 4], t);
        }
        __syncthreads();           // Xq(qd) visible
#pragma unroll
        for (int ks = 0; ks < 4; ++ks) {
            int kk = qd * 4 + ks;
            bf16x8 a0 = ldfrag(&Xq[rt * 16 + l16][ks * 64 + quad * 8]);
            bf16x8 a1 = ldfrag(&Xq[rt * 16 + l16][ks * 64 + 32 + quad * 8]);
#pragma unroll
            for (int j = 0; j < 6; ++j) {
                int n = g * 6 + j;
                const u16* wrow = wqkv + (size_t)(n * 16 + l16) * DD + kk * 64;
                bf16x8 b0 = ldfrag(wrow + quad * 8);        // L2-hit global
                bf16x8 b1 = ldfrag(wrow + 32 + quad * 8);
                acc[j] = MFMA(a0, b0, acc[j]);
                acc[j] = MFMA(a1, b1, acc[j]);
            }
        }
    }
    __syncthreads();               // compute done; Xq free for Vbuf overlay

    // epilogue: global row = rowbase + rt*16 + quad*4 + rr; col = n*16 + l16
    u16 (*Vbuf)[264] = Xq;
#pragma unroll
    for (int rr = 0; rr < 4; ++rr) {
        int rloc = rt * 16 + quad * 4 + rr;
        size_t m = (size_t)(rowbase + rloc);
        if (g == 0) {
            st4s(&q[m * DK + l16], acc[0][rr] * QSCALE, acc[1][rr] * QSCALE,
                                   acc[2][rr] * QSCALE, acc[3][rr] * QSCALE);
            st2s(&k[m * DK + l16], acc[4][rr], acc[5][rr]);
        } else {
            st2s(&k[m * DK + 32 + l16], acc[0][rr], acc[1][rr]);
            st4s(&Vbuf[rloc][l16], acc[2][rr], acc[3][rr],
                                   acc[4][rr], acc[5][rr]);
        }
    }
    __syncthreads();
    {
        const int dk = tid >> 3;
        const int sc = (tid & 7) * 8;
        const int bh = rowbase >> 11;
        const int s0 = rowbase & 2047;
        union { u16 s[8]; uint4 u; } t;
#pragma unroll
        for (int u = 0; u < 8; ++u) t.s[u] = Vbuf[sc + u][dk];
        *(uint4*)(vT + ((size_t)(bh * DK + dk)) * SS + s0 + sc) = t.u;
    }
}

// ---------------------------------------------------------------------------
// Kernel 2: flash attention v5 (byte-frozen from the 483 us run). QBLK=128,
// 512 thr / 8 waves, KVBLK=64 serial staging (2 barriers), Q in regs, lazy
// softmax (lane-local defer-max, per-lane partial sums), P via LDS, setprio.
// ---------------------------------------------------------------------------
__global__ __launch_bounds__(512) void flash_attn(
    const u16* __restrict__ q, const u16* __restrict__ k,
    const u16* __restrict__ vT, u16* __restrict__ ao)
{
    __shared__ __align__(16) u16 Ks[64][72];       //  9.2 KB
    __shared__ __align__(16) u16 Vt[64][72];       //  9.2 KB  Vt[dk][t]
    __shared__ __align__(16) u16 Ps[8][16][72];    // 18.4 KB per-wave P tiles
    const int tid  = threadIdx.x;
    const int w    = tid >> 6;
    const int lane = tid & 63;
    const int quad = lane >> 4;
    const int l16  = lane & 15;
    const int rg   = w >> 2;       // row group (0/1) within 128-row tile
    const int rt   = w & 3;        // row tile within group
    const int qt   = blockIdx.x;   // 0..15
    const int bh   = blockIdx.y;
    const size_t kbase = (size_t)bh * SS * DK;     // q,k layout [bh*S + t][64]
    const size_t vbase = (size_t)bh * DK * SS;     // vT layout [bh*64 + dk][S]

    // Q fragments: invariant over kt -> registers, once
    const u16* qrow = q + kbase +
        (size_t)(qt * 128 + rg * 64 + rt * 16 + l16) * DK;
    const bf16x8 qa0 = ldfrag(qrow + quad * 8);
    const bf16x8 qa1 = ldfrag(qrow + 32 + quad * 8);

    float m_i[4], l_part[4];
    floatx4 acc_o[4];
#pragma unroll
    for (int r = 0; r < 4; ++r) { m_i[r] = -INFINITY; l_part[r] = 0.f; }
#pragma unroll
    for (int n = 0; n < 4; ++n) acc_o[n] = (floatx4){0.f,0.f,0.f,0.f};

    for (int kt = 0; kt < SS / 64; ++kt) {
        // stage K tile [64 t][64 dk] and Vt tile [64 dk][64 t]
        {
            int r  = tid >> 3, c8 = tid & 7;
            *(uint4*)&Ks[r][c8 * 8] =
                *(const uint4*)(k + kbase + (size_t)(kt * 64 + r) * DK + c8 * 8);
            *(uint4*)&Vt[r][c8 * 8] =
                *(const uint4*)(vT + vbase + (size_t)r * SS + kt * 64 + c8 * 8);
        }
        __syncthreads();

        // scores (log2 units)
        floatx4 sc[4];
        __builtin_amdgcn_s_setprio(1);
#pragma unroll
        for (int n = 0; n < 4; ++n) {
            sc[n] = (floatx4){0.f,0.f,0.f,0.f};
            bf16x8 b0 = ldfrag(&Ks[n * 16 + l16][quad * 8]);
            bf16x8 b1 = ldfrag(&Ks[n * 16 + l16][32 + quad * 8]);
            sc[n] = MFMA(qa0, b0, sc[n]);
            sc[n] = MFMA(qa1, b1, sc[n]);
        }
        __builtin_amdgcn_s_setprio(0);

        // lane-local defer-max check (no shuffles in common path)
        float lm[4];
#pragma unroll
        for (int r = 0; r < 4; ++r)
            lm[r] = fmaxf(fmaxf(sc[0][r], sc[1][r]), fmaxf(sc[2][r], sc[3][r]));
        int ok = (lm[0] <= m_i[0] + 8.f) & (lm[1] <= m_i[1] + 8.f) &
                 (lm[2] <= m_i[2] + 8.f) & (lm[3] <= m_i[3] + 8.f);
        if (!__all(ok)) {          // rare: true row max via butterfly + rescale
#pragma unroll
            for (int r = 0; r < 4; ++r) {
                float rm = lm[r];
#pragma unroll
                for (int off = 1; off < 16; off <<= 1)
                    rm = fmaxf(rm, __shfl_xor(rm, off, 64));
                float mnew  = fmaxf(m_i[r], rm);
                float alpha = __builtin_amdgcn_exp2f(m_i[r] - mnew);
#pragma unroll
                for (int n = 0; n < 4; ++n) acc_o[n][r] *= alpha;
                l_part[r] *= alpha;
                m_i[r]     = mnew;
            }
        }
        // P = exp2(S - m); per-lane partial row sums (no shuffles); P -> LDS
#pragma unroll
        for (int r = 0; r < 4; ++r) {
            float mi = m_i[r];
            float p0 = __builtin_amdgcn_exp2f(sc[0][r] - mi);
            float p1 = __builtin_amdgcn_exp2f(sc[1][r] - mi);
            float p2 = __builtin_amdgcn_exp2f(sc[2][r] - mi);
            float p3 = __builtin_amdgcn_exp2f(sc[3][r] - mi);
            l_part[r] += (p0 + p1) + (p2 + p3);
            st4s(&Ps[w][quad * 4 + r][l16], p0, p1, p2, p3);
        }
        // Ps per-wave private: no barrier (compiler inserts lgkmcnt)

        // PV
        __builtin_amdgcn_s_setprio(1);
#pragma unroll
        for (int kc = 0; kc < 2; ++kc) {
            bf16x8 a = ldfrag(&Ps[w][l16][kc * 32 + quad * 8]);
#pragma unroll
            for (int n = 0; n < 4; ++n) {
                bf16x8 b = ldfrag(&Vt[n * 16 + l16][kc * 32 + quad * 8]);
                acc_o[n] = MFMA(a, b, acc_o[n]);
            }
        }
        __builtin_amdgcn_s_setprio(0);
        __syncthreads();                            // done reading Ks/Vt
    }

    // epilogue: single butterfly for the row sums, then -> ao[B,S,H*64] bf16
    const int b = bh >> 4, h = bh & 15;
#pragma unroll
    for (int r = 0; r < 4; ++r) {
        float l = l_part[r];
#pragma unroll
        for (int off = 1; off < 16; off <<= 1)
            l += __shfl_xor(l, off, 64);
        float rl = __builtin_amdgcn_rcpf(l);
        int srow = qt * 128 + rg * 64 + rt * 16 + quad * 4 + r;
        size_t base = ((size_t)(b * SS + srow)) * (HH * DK) + h * 64;
        st4s(&ao[base + l16], acc_o[0][r] * rl, acc_o[1][r] * rl,
                              acc_o[2][r] * rl, acc_o[3][r] * rl);
    }
}

// ---------------------------------------------------------------------------
// Kernel 3: output projection (byte-frozen R3/R10-measured v1: 64x64, 256 thr,
// grid 1024 -> 4 blocks/CU staging overlap).
// ---------------------------------------------------------------------------
__global__ __launch_bounds__(256) void out_proj(
    const u16* __restrict__ ao, const u16* __restrict__ wo_bf,
    float* __restrict__ out)
{
    __shared__ __align__(16) u16 As[64][72];
    __shared__ __align__(16) u16 Bs[64][72];
    const int tid  = threadIdx.x;
    const int w    = tid >> 6;
    const int lane = tid & 63;
    const int quad = lane >> 4;
    const int l16  = lane & 15;
    const int mt = blockIdx.y;
    const int nt = blockIdx.x;

    floatx4 acc[4];
#pragma unroll
    for (int n = 0; n < 4; ++n) acc[n] = (floatx4){0.f,0.f,0.f,0.f};

    for (int k0 = 0; k0 < DD; k0 += 64) {
#pragma unroll
        for (int it = 0; it < 2; ++it) {
            int li = tid + it * 256;
            int r  = li >> 3, c8 = li & 7;
            *(uint4*)&As[r][c8 * 8] =
                *(const uint4*)(ao + (size_t)(mt * 64 + r) * DD + k0 + c8 * 8);
            *(uint4*)&Bs[r][c8 * 8] =
                *(const uint4*)(wo_bf + (size_t)(nt * 64 + r) * DD + k0 + c8 * 8);
        }
        __syncthreads();

        bf16x8 a0 = ldfrag(&As[w * 16 + l16][quad * 8]);
        bf16x8 a1 = ldfrag(&As[w * 16 + l16][32 + quad * 8]);
#pragma unroll
        for (int n = 0; n < 4; ++n) {
            bf16x8 b0 = ldfrag(&Bs[n * 16 + l16][quad * 8]);
            bf16x8 b1 = ldfrag(&Bs[n * 16 + l16][32 + quad * 8]);
            acc[n] = MFMA(a0, b0, acc[n]);
            acc[n] = MFMA(a1, b1, acc[n]);
        }
        __syncthreads();
    }

#pragma unroll
    for (int r = 0; r < 4; ++r) {
        int row = mt * 64 + w * 16 + quad * 4 + r;
#pragma unroll
        for (int n = 0; n < 4; ++n)
            out[(size_t)row * DD + nt * 64 + n * 16 + l16] = acc[n][r];
    }
}

// ---------------------------------------------------------------------------
extern "C" void kernel_launch(void* const* d_in, const int* in_sizes, int n_in,
                              void* d_out, int out_size, void* d_ws, size_t ws_size,
                              hipStream_t stream) {
    const float* x  = (const float*)d_in[0];
    const float* wq = (const float*)d_in[1];
    const float* wk = (const float*)d_in[2];
    const float* wv = (const float*)d_in[3];
    const float* wo = (const float*)d_in[4];
    float* out = (float*)d_out;

    u16* q     = (u16*)d_ws;
    u16* k     = q    + (size_t)BHS * DK;
    u16* vT    = k    + (size_t)BHS * DK;
    u16* ao    = vT   + (size_t)BHS * DK;
    u16* wqkv  = ao   + (size_t)BHS * DK;
    u16* wo_bf = wqkv + (size_t)192 * DD;

    convert_w<<<dim3((WQKV_CHUNKS + WO_CHUNKS) / 256), dim3(256), 0, stream>>>(
        wq, wk, wv, wo, wqkv, wo_bf);
    qkv_proj<<<dim3(BHS / 64), dim3(512), 0, stream>>>(x, wqkv, q, k, vT);
    flash_attn<<<dim3(SS / 128, BB * HH), dim3(512), 0, stream>>>(q, k, vT, ao);
    out_proj<<<dim3(DD / 64, (BB * SS) / 64), dim3(256), 0, stream>>>(ao, wo_bf, out);
}

// Round 13
// 477.648 us; speedup vs baseline: 1.2257x; 1.2257x over previous
//
#include <hip/hip_runtime.h>
#include <math.h>

// Shapes (fixed)
#define BB 2
#define HH 16
#define SS 2048
#define DD 1024
#define DK 64
#define BHS (BB*HH*SS)          // 65536
#define QSCALE 0.04508422f      // log2(e)/sqrt(1024): folded into q so softmax uses exp2

typedef short  bf16x8  __attribute__((ext_vector_type(8)));
typedef float  floatx4 __attribute__((ext_vector_type(4)));
typedef unsigned short u16;

#define MFMA(a,b,c) __builtin_amdgcn_mfma_f32_16x16x32_bf16((a),(b),(c),0,0,0)

// hardware packed conversion: dst.lo = bf16(lo), dst.hi = bf16(hi), RNE
__device__ __forceinline__ unsigned cvt_pk_bf16(float lo, float hi) {
    unsigned r;
    asm("v_cvt_pk_bf16_f32 %0, %1, %2" : "=v"(r) : "v"(lo), "v"(hi));
    return r;
}
__device__ __forceinline__ bf16x8 ldfrag(const u16* p) {
    union { uint4 u; bf16x8 b; } c;
    c.u = *(const uint4*)p;
    return c.b;
}
__device__ __forceinline__ void stbf4(u16* p, float4 t) {  // 4xf32 -> 4xbf16, 8B store
    union { unsigned u[2]; uint2 v; } c;
    c.u[0] = cvt_pk_bf16(t.x, t.y);
    c.u[1] = cvt_pk_bf16(t.z, t.w);
    *(uint2*)p = c.v;
}
// 4 f32 -> bf16 at p[0], p[16], p[32], p[48]  (C-fragment col stride 16)
__device__ __forceinline__ void st4s(u16* p, float a, float b, float c, float d) {
    unsigned x = cvt_pk_bf16(a, b), y = cvt_pk_bf16(c, d);
    p[0]  = (u16)x; p[16] = (u16)(x >> 16);
    p[32] = (u16)y; p[48] = (u16)(y >> 16);
}
// 2 f32 -> bf16 at p[0], p[16]
__device__ __forceinline__ void st2s(u16* p, float a, float b) {
    unsigned x = cvt_pk_bf16(a, b);
    p[0]  = (u16)x; p[16] = (u16)(x >> 16);
}

// ---------------------------------------------------------------------------
// Kernel 0: one-shot weight conversion fp32->bf16 (frozen).
// ---------------------------------------------------------------------------
#define WQKV_CHUNKS (192*1024/4)     // 49152 float4 chunks
#define WO_CHUNKS   (1024*1024/4)    // 262144
__global__ __launch_bounds__(256) void convert_w(
    const float* __restrict__ wq, const float* __restrict__ wk,
    const float* __restrict__ wv, const float* __restrict__ wo,
    u16* __restrict__ wqkv, u16* __restrict__ wo_bf)
{
    int i = blockIdx.x * 256 + threadIdx.x;
    if (i < WQKV_CHUNKS) {
        int r = i >> 8;            // row 0..191 (256 float4 per row)
        int c = i & 255;
        const float* src = (r < 64) ? wq : ((r < 128) ? wk : wv);
        float4 t = *(const float4*)(src + (size_t)(r & 63) * DD + c * 4);
        stbf4(wqkv + (size_t)r * DD + c * 4, t);
    } else if (i < WQKV_CHUNKS + WO_CHUNKS) {
        int j = i - WQKV_CHUNKS;
        float4 t = *(const float4*)(wo + (size_t)j * 4);
        stbf4(wo_bf + (size_t)j * 4, t);
    }
}

// ---------------------------------------------------------------------------
// Kernel 1: QKV projection v5 — DRAM-burst X staging + W through LDS
// (byte-revert to the R10/483 us version; v6's W-direct-global regressed
// 120->227 us: dependent per-MFMA global gathers serialized the inner loop).
// ---------------------------------------------------------------------------
__global__ __launch_bounds__(512) void qkv_proj(
    const float* __restrict__ x, const u16* __restrict__ wqkv,
    u16* __restrict__ q, u16* __restrict__ k, u16* __restrict__ vT)
{
    __shared__ __align__(16) u16 Xq[64][264];   // 33.8 KB quarter-K X panel
    __shared__ __align__(16) u16 Ws[192][72];   // 27.6 KB W k-slice
    const int tid  = threadIdx.x;
    const int w    = tid >> 6;
    const int lane = tid & 63;
    const int quad = lane >> 4;
    const int l16  = lane & 15;
    const int rt   = w & 3;
    const int g    = w >> 2;
    const int rowbase = blockIdx.x * 64;

    floatx4 acc[6];
#pragma unroll
    for (int j = 0; j < 6; ++j) acc[j] = (floatx4){0.f,0.f,0.f,0.f};

    for (int qd = 0; qd < 4; ++qd) {
        // stage X quarter: 64 rows x 256 cols fp32 -> bf16 (1 KB row-runs)
#pragma unroll
        for (int it = 0; it < 8; ++it) {
            int li = tid + it * 512;
            int r  = li >> 6, c4 = li & 63;
            float4 t = *(const float4*)(x + (size_t)(rowbase + r) * DD
                                          + qd * 256 + c4 * 4);
            stbf4(&Xq[r][c4 * 4], t);
        }
        for (int ks = 0; ks < 4; ++ks) {
            int kk = qd * 4 + ks;
            // stage W k-slice 192x64 (1536 uint4, 3/thread)
#pragma unroll
            for (int it = 0; it < 3; ++it) {
                int li = tid + it * 512;
                int r  = li >> 3, c8 = li & 7;
                *(uint4*)&Ws[r][c8 * 8] =
                    *(const uint4*)(wqkv + (size_t)r * DD + kk * 64 + c8 * 8);
            }
            __syncthreads();    // Xq (ks==0) and Ws visible

            bf16x8 a0 = ldfrag(&Xq[rt * 16 + l16][ks * 64 + quad * 8]);
            bf16x8 a1 = ldfrag(&Xq[rt * 16 + l16][ks * 64 + 32 + quad * 8]);
#pragma unroll
            for (int j = 0; j < 6; ++j) {
                int n = g * 6 + j;
                bf16x8 b0 = ldfrag(&Ws[n * 16 + l16][quad * 8]);
                bf16x8 b1 = ldfrag(&Ws[n * 16 + l16][32 + quad * 8]);
                acc[j] = MFMA(a0, b0, acc[j]);
                acc[j] = MFMA(a1, b1, acc[j]);
            }
            __syncthreads();    // Ws/Xq consumed; safe to restage
        }
    }

    // epilogue (identical to measured kernel; Vbuf overlays Ws)
    u16 (*Vbuf)[72] = (u16 (*)[72])&Ws[0][0];
#pragma unroll
    for (int rr = 0; rr < 4; ++rr) {
        int rloc = rt * 16 + quad * 4 + rr;
        size_t m = (size_t)(rowbase + rloc);
        if (g == 0) {
            st4s(&q[m * DK + l16], acc[0][rr] * QSCALE, acc[1][rr] * QSCALE,
                                   acc[2][rr] * QSCALE, acc[3][rr] * QSCALE);
            st2s(&k[m * DK + l16], acc[4][rr], acc[5][rr]);
        } else {
            st2s(&k[m * DK + 32 + l16], acc[0][rr], acc[1][rr]);
            st4s(&Vbuf[rloc][l16], acc[2][rr], acc[3][rr],
                                   acc[4][rr], acc[5][rr]);
        }
    }
    __syncthreads();
    {
        const int dk = tid >> 3;
        const int sc = (tid & 7) * 8;
        const int bh = rowbase >> 11;
        const int s0 = rowbase & 2047;
        union { u16 s[8]; uint4 u; } t;
#pragma unroll
        for (int u = 0; u < 8; ++u) t.s[u] = Vbuf[sc + u][dk];
        *(uint4*)(vT + ((size_t)(bh * DK + dk)) * SS + s0 + sc) = t.u;
    }
}

// ---------------------------------------------------------------------------
// Kernel 2: flash attention v5 + XCD chunked swizzle (T1).
// Linear id L = bh*16+qt round-robins XCDs -> the 16 qt-blocks sharing one
// bh's K/V (512 KB) land on 8 different L2s (~8x K/V over-fetch). Swizzle
// S=(L&7)*64+(L>>3) gives each XCD 4 bh x 16 qt -> 2 MB K/V, L2-resident.
// Inner loop byte-identical to the 483 us run.
// ---------------------------------------------------------------------------
__global__ __launch_bounds__(512) void flash_attn(
    const u16* __restrict__ q, const u16* __restrict__ k,
    const u16* __restrict__ vT, u16* __restrict__ ao)
{
    __shared__ __align__(16) u16 Ks[64][72];       //  9.2 KB
    __shared__ __align__(16) u16 Vt[64][72];       //  9.2 KB  Vt[dk][t]
    __shared__ __align__(16) u16 Ps[8][16][72];    // 18.4 KB per-wave P tiles
    const int tid  = threadIdx.x;
    const int w    = tid >> 6;
    const int lane = tid & 63;
    const int quad = lane >> 4;
    const int l16  = lane & 15;
    const int rg   = w >> 2;       // row group (0/1) within 128-row tile
    const int rt   = w & 3;        // row tile within group
    // XCD chunked swizzle (bijective: 512 wgs, 512%8==0)
    const int L  = blockIdx.y * 16 + blockIdx.x;   // 0..511
    const int S  = (L & 7) * 64 + (L >> 3);
    const int qt = S & 15;
    const int bh = S >> 4;
    const size_t kbase = (size_t)bh * SS * DK;     // q,k layout [bh*S + t][64]
    const size_t vbase = (size_t)bh * DK * SS;     // vT layout [bh*64 + dk][S]

    // Q fragments: invariant over kt -> registers, once
    const u16* qrow = q + kbase +
        (size_t)(qt * 128 + rg * 64 + rt * 16 + l16) * DK;
    const bf16x8 qa0 = ldfrag(qrow + quad * 8);
    const bf16x8 qa1 = ldfrag(qrow + 32 + quad * 8);

    float m_i[4], l_part[4];
    floatx4 acc_o[4];
#pragma unroll
    for (int r = 0; r < 4; ++r) { m_i[r] = -INFINITY; l_part[r] = 0.f; }
#pragma unroll
    for (int n = 0; n < 4; ++n) acc_o[n] = (floatx4){0.f,0.f,0.f,0.f};

    for (int kt = 0; kt < SS / 64; ++kt) {
        // stage K tile [64 t][64 dk] and Vt tile [64 dk][64 t]
        {
            int r  = tid >> 3, c8 = tid & 7;
            *(uint4*)&Ks[r][c8 * 8] =
                *(const uint4*)(k + kbase + (size_t)(kt * 64 + r) * DK + c8 * 8);
            *(uint4*)&Vt[r][c8 * 8] =
                *(const uint4*)(vT + vbase + (size_t)r * SS + kt * 64 + c8 * 8);
        }
        __syncthreads();

        // scores (log2 units)
        floatx4 sc[4];
        __builtin_amdgcn_s_setprio(1);
#pragma unroll
        for (int n = 0; n < 4; ++n) {
            sc[n] = (floatx4){0.f,0.f,0.f,0.f};
            bf16x8 b0 = ldfrag(&Ks[n * 16 + l16][quad * 8]);
            bf16x8 b1 = ldfrag(&Ks[n * 16 + l16][32 + quad * 8]);
            sc[n] = MFMA(qa0, b0, sc[n]);
            sc[n] = MFMA(qa1, b1, sc[n]);
        }
        __builtin_amdgcn_s_setprio(0);

        // lane-local defer-max check (no shuffles in common path)
        float lm[4];
#pragma unroll
        for (int r = 0; r < 4; ++r)
            lm[r] = fmaxf(fmaxf(sc[0][r], sc[1][r]), fmaxf(sc[2][r], sc[3][r]));
        int ok = (lm[0] <= m_i[0] + 8.f) & (lm[1] <= m_i[1] + 8.f) &
                 (lm[2] <= m_i[2] + 8.f) & (lm[3] <= m_i[3] + 8.f);
        if (!__all(ok)) {          // rare: true row max via butterfly + rescale
#pragma unroll
            for (int r = 0; r < 4; ++r) {
                float rm = lm[r];
#pragma unroll
                for (int off = 1; off < 16; off <<= 1)
                    rm = fmaxf(rm, __shfl_xor(rm, off, 64));
                float mnew  = fmaxf(m_i[r], rm);
                float alpha = __builtin_amdgcn_exp2f(m_i[r] - mnew);
#pragma unroll
                for (int n = 0; n < 4; ++n) acc_o[n][r] *= alpha;
                l_part[r] *= alpha;
                m_i[r]     = mnew;
            }
        }
        // P = exp2(S - m); per-lane partial row sums (no shuffles); P -> LDS
#pragma unroll
        for (int r = 0; r < 4; ++r) {
            float mi = m_i[r];
            float p0 = __builtin_amdgcn_exp2f(sc[0][r] - mi);
            float p1 = __builtin_amdgcn_exp2f(sc[1][r] - mi);
            float p2 = __builtin_amdgcn_exp2f(sc[2][r] - mi);
            float p3 = __builtin_amdgcn_exp2f(sc[3][r] - mi);
            l_part[r] += (p0 + p1) + (p2 + p3);
            st4s(&Ps[w][quad * 4 + r][l16], p0, p1, p2, p3);
        }
        // Ps per-wave private: no barrier (compiler inserts lgkmcnt)

        // PV
        __builtin_amdgcn_s_setprio(1);
#pragma unroll
        for (int kc = 0; kc < 2; ++kc) {
            bf16x8 a = ldfrag(&Ps[w][l16][kc * 32 + quad * 8]);
#pragma unroll
            for (int n = 0; n < 4; ++n) {
                bf16x8 b = ldfrag(&Vt[n * 16 + l16][kc * 32 + quad * 8]);
                acc_o[n] = MFMA(a, b, acc_o[n]);
            }
        }
        __builtin_amdgcn_s_setprio(0);
        __syncthreads();                            // done reading Ks/Vt
    }

    // epilogue: single butterfly for the row sums, then -> ao[B,S,H*64] bf16
    const int b = bh >> 4, h = bh & 15;
#pragma unroll
    for (int r = 0; r < 4; ++r) {
        float l = l_part[r];
#pragma unroll
        for (int off = 1; off < 16; off <<= 1)
            l += __shfl_xor(l, off, 64);
        float rl = __builtin_amdgcn_rcpf(l);
        int srow = qt * 128 + rg * 64 + rt * 16 + quad * 4 + r;
        size_t base = ((size_t)(b * SS + srow)) * (HH * DK) + h * 64;
        st4s(&ao[base + l16], acc_o[0][r] * rl, acc_o[1][r] * rl,
                              acc_o[2][r] * rl, acc_o[3][r] * rl);
    }
}

// ---------------------------------------------------------------------------
// Kernel 3: output projection v1 + XCD chunked swizzle (T1).
// Swizzle S=(L&7)*128+(L>>3): each XCD owns 8 mt x 16 nt -> wo_bf (2 MB)
// + its A rows (1 MB) L2-resident; kills the ~8x A/B cross-XCD re-fetch.
// Inner loop byte-identical to the 483 us run.
// ---------------------------------------------------------------------------
__global__ __launch_bounds__(256) void out_proj(
    const u16* __restrict__ ao, const u16* __restrict__ wo_bf,
    float* __restrict__ out)
{
    __shared__ __align__(16) u16 As[64][72];
    __shared__ __align__(16) u16 Bs[64][72];
    const int tid  = threadIdx.x;
    const int w    = tid >> 6;
    const int lane = tid & 63;
    const int quad = lane >> 4;
    const int l16  = lane & 15;
    // XCD chunked swizzle (bijective: 1024 wgs)
    const int L  = blockIdx.y * 16 + blockIdx.x;   // 0..1023
    const int S  = (L & 7) * 128 + (L >> 3);
    const int nt = S & 15;
    const int mt = S >> 4;

    floatx4 acc[4];
#pragma unroll
    for (int n = 0; n < 4; ++n) acc[n] = (floatx4){0.f,0.f,0.f,0.f};

    for (int k0 = 0; k0 < DD; k0 += 64) {
#pragma unroll
        for (int it = 0; it < 2; ++it) {
            int li = tid + it * 256;
            int r  = li >> 3, c8 = li & 7;
            *(uint4*)&As[r][c8 * 8] =
                *(const uint4*)(ao + (size_t)(mt * 64 + r) * DD + k0 + c8 * 8);
            *(uint4*)&Bs[r][c8 * 8] =
                *(const uint4*)(wo_bf + (size_t)(nt * 64 + r) * DD + k0 + c8 * 8);
        }
        __syncthreads();

        bf16x8 a0 = ldfrag(&As[w * 16 + l16][quad * 8]);
        bf16x8 a1 = ldfrag(&As[w * 16 + l16][32 + quad * 8]);
#pragma unroll
        for (int n = 0; n < 4; ++n) {
            bf16x8 b0 = ldfrag(&Bs[n * 16 + l16][quad * 8]);
            bf16x8 b1 = ldfrag(&Bs[n * 16 + l16][32 + quad * 8]);
            acc[n] = MFMA(a0, b0, acc[n]);
            acc[n] = MFMA(a1, b1, acc[n]);
        }
        __syncthreads();
    }

#pragma unroll
    for (int r = 0; r < 4; ++r) {
        int row = mt * 64 + w * 16 + quad * 4 + r;
#pragma unroll
        for (int n = 0; n < 4; ++n)
            out[(size_t)row * DD + nt * 64 + n * 16 + l16] = acc[n][r];
    }
}

// ---------------------------------------------------------------------------
extern "C" void kernel_launch(void* const* d_in, const int* in_sizes, int n_in,
                              void* d_out, int out_size, void* d_ws, size_t ws_size,
                              hipStream_t stream) {
    const float* x  = (const float*)d_in[0];
    const float* wq = (const float*)d_in[1];
    const float* wk = (const float*)d_in[2];
    const float* wv = (const float*)d_in[3];
    const float* wo = (const float*)d_in[4];
    float* out = (float*)d_out;

    u16* q     = (u16*)d_ws;
    u16* k     = q    + (size_t)BHS * DK;
    u16* vT    = k    + (size_t)BHS * DK;
    u16* ao    = vT   + (size_t)BHS * DK;
    u16* wqkv  = ao   + (size_t)BHS * DK;
    u16* wo_bf = wqkv + (size_t)192 * DD;

    convert_w<<<dim3((WQKV_CHUNKS + WO_CHUNKS) / 256), dim3(256), 0, stream>>>(
        wq, wk, wv, wo, wqkv, wo_bf);
    qkv_proj<<<dim3(BHS / 64), dim3(512), 0, stream>>>(x, wqkv, q, k, vT);
    flash_attn<<<dim3(SS / 128, BB * HH), dim3(512), 0, stream>>>(q, k, vT, ao);
    out_proj<<<dim3(DD / 64, (BB * SS) / 64), dim3(256), 0, stream>>>(ao, wo_bf, out);
}